// Round 12
// baseline (224.061 us; speedup 1.0000x reference)
//
#include <hip/hip_runtime.h>
#include <hip/hip_bf16.h>

typedef float f32x4 __attribute__((ext_vector_type(4)));
typedef float f32x16 __attribute__((ext_vector_type(16)));
typedef unsigned int u32;
typedef u32 u32x2 __attribute__((ext_vector_type(2)));
typedef u32 u32x4 __attribute__((ext_vector_type(4)));
typedef short bf16x8 __attribute__((ext_vector_type(8)));   // 8 bf16 (guide §3 convention)

#define SD 8192      // S*D
#define NROWS 8192   // B*N
#define NN 4096      // N
#define DD 2048      // D
#define DTP 4104     // padded u32 row stride for dT (+8 u32 -> A-frag reads conflict-free)

__device__ __forceinline__ u32 bfr(float f) {   // f32 -> bf16 bits, RNE (K0 only)
    u32 u = __float_as_uint(f);
    return (u + 0x7fffu + ((u >> 16) & 1u)) >> 16;
}
__device__ __forceinline__ float blo(u32 u) { return __uint_as_float(u << 16); }
__device__ __forceinline__ float bhi(u32 u) { return __uint_as_float(u & 0xffff0000u); }

// K0: Wbf[k][j] = bf16( w[j][k] * (gamma[j]+1) ), k 0..31; rows 24..31 zeroed
// (they feed MFMA B-cols 24..31 whose outputs are discarded -- must be finite).
__global__ void k0_prep(const float* __restrict__ gamma,
                        const float* __restrict__ daf,
                        const float* __restrict__ dbf,
                        unsigned short* __restrict__ Wbf) {
    int idx = blockIdx.x * 256 + threadIdx.x;
    if (idx >= 32 * SD) return;
    int k = idx >> 13;
    int j = idx & (SD - 1);
    unsigned short v = 0;
    if (k < 24) {
        float g = gamma[j] + 1.0f;
        float w = (k < 20) ? daf[j * 20 + k] : dbf[j * 4 + (k - 20)];
        v = (unsigned short)bfr(w * g);
    }
    Wbf[(size_t)k * SD + j] = v;
}

// KF: fused, spill-proof (all load-carrying loops rolled), projection on MFMA.
// Block = 4 rows, 512 threads (8 waves), ~70 KiB LDS -> 2 blocks/CU.
// P1: rows f32->reg (ssq via packed FMA) -> bf16 LDS via v_cvt_pk_bf16_f32.
// P2: projection as MFMA 32x32x16: wave wv owns j-slice 1024 (64 K-steps);
//     A row = lane&31 (dup &3), k = (lane>>5)*8+i  [standard M-major layout];
//     B col = lane&31 (k-col), k likewise, read from L2-resident bf16 weights.
//     C (m74/m101-verified): col=lane&31, row=(reg&3)+8*(reg>>2)+4*(lane>>5)
//     -> valid rows 0..3 live in lanes 0..31, regs 0..3. 8 partials -> LDS.
// P3: wave 0: 20-iter sinkhorn + coeff.
// P4: mix from LDS with f32x4 vector FMAs (v_pk_fma_f32), nt stores.
__global__ __launch_bounds__(512) void kf(const float* __restrict__ res,
                                          const unsigned short* __restrict__ Wbf,
                                          const float* __restrict__ sa,
                                          const float* __restrict__ sb,
                                          const float* __restrict__ pbs,
                                          const float* __restrict__ rsc,
                                          const float* __restrict__ hps,
                                          float* __restrict__ out) {
    __shared__ u32 dTp[4][DTP];        // packed bf16x2; 65.7 KiB
    __shared__ float pc[8][4][32];     // per-wave partial C
    __shared__ float red[4][32];
    __shared__ float ssqw[8];
    __shared__ float coefS[4][16];

    const int tid  = threadIdx.x;
    const int wv   = tid >> 6;
    const int lane = tid & 63;
    const int row0 = blockIdx.x * 4;
    const int b    = row0 >> 12;
    const int n0   = row0 & (NN - 1);
    const int r    = tid >> 7;          // staging/mix row 0..3
    const int rem  = tid & 127;

    // ---------- P1: stage 4 rows, ssq, pack bf16 (cvt_pk) ----------
    const float* rowbase = res + ((size_t)(b * 4) * NN + (n0 + r)) * DD;
    f32x4 ssq4 = {0.f, 0.f, 0.f, 0.f};
#pragma unroll 1
    for (int h = 0; h < 4; ++h) {
        f32x4 v[4];
#pragma unroll
        for (int i = 0; i < 4; ++i) {
            const int q  = h * 4 + i;
            const int j0 = (rem + 128 * q) * 4;
            const int s  = j0 >> 11, d = j0 & 2047;
            v[i] = __builtin_nontemporal_load((const f32x4*)(rowbase + (size_t)s * NN * DD + d));
        }
#pragma unroll
        for (int i = 0; i < 4; ++i) {
            ssq4 += v[i] * v[i];
            u32 lo, hi;
            asm("v_cvt_pk_bf16_f32 %0, %1, %2" : "=v"(lo) : "v"(v[i].x), "v"(v[i].y));
            asm("v_cvt_pk_bf16_f32 %0, %1, %2" : "=v"(hi) : "v"(v[i].z), "v"(v[i].w));
            const int jp = (rem + 128 * (h * 4 + i)) * 2;
            *(u32x2*)&dTp[r][jp] = (u32x2){lo, hi};
        }
    }
    float ssq = ssq4.x + ssq4.y + ssq4.z + ssq4.w;
    ssq += __shfl_xor(ssq, 1);  ssq += __shfl_xor(ssq, 2);
    ssq += __shfl_xor(ssq, 4);  ssq += __shfl_xor(ssq, 8);
    ssq += __shfl_xor(ssq, 16); ssq += __shfl_xor(ssq, 32);
    if (lane == 0) ssqw[wv] = ssq;
    __syncthreads();

    // ---------- P2: projection via MFMA ----------
    {
        f32x16 acc;
#pragma unroll
        for (int i = 0; i < 16; ++i) acc[i] = 0.f;
        const u32* abase = &dTp[lane & 3][wv * 512 + (lane >> 5) * 4];
        const unsigned short* wbase = Wbf + (size_t)(lane & 31) * SD + wv * 1024 + (lane >> 5) * 8;
#pragma unroll 2
        for (int st = 0; st < 64; ++st) {
            const u32x4 au = *(const u32x4*)(abase + st * 8);
            const u32x4 bu = *(const u32x4*)(wbase + st * 16);
            acc = __builtin_amdgcn_mfma_f32_32x32x16_bf16(
                __builtin_bit_cast(bf16x8, au), __builtin_bit_cast(bf16x8, bu), acc, 0, 0, 0);
        }
        if (lane < 32) {
#pragma unroll
            for (int g = 0; g < 4; ++g) pc[wv][g][lane] = acc[g];
        }
    }
    __syncthreads();
    if (tid < 128) {
        const int rr = tid >> 5, c = tid & 31;
        float s = 0.f;
#pragma unroll
        for (int w = 0; w < 8; ++w) s += pc[w][rr][c];
        red[rr][c] = s;
    }
    __syncthreads();

    // ---------- P3: sinkhorn + coeff (wave 0; 4 rows x 16 lanes) ----------
    if (wv == 0) {
        const int rr = lane >> 4, l = lane & 15, s = l >> 2, t = l & 3;
        const float ssqr  = ssqw[2 * rr] + ssqw[2 * rr + 1];
        const float scale = 90.50966799187809f / fmaxf(sqrtf(ssqr), 1e-12f);
        const float P  = red[rr][s * 5 + t + 1];
        const float P0 = red[rr][s * 5];
        const float Pb = red[rr][20 + t];
        float la = scale * P * rsc[0] + sa[s * 5 + t + 1];
        const float a0 = scale * P0 * pbs[0] + sa[s * 5];
        const float ap = 1.f / (1.f + __expf(-a0));
        const float bt = 2.f / (1.f + __expf(-(scale * Pb * hps[0] + sb[t])));
#pragma unroll
        for (int it = 0; it < 20; ++it) {
            float m = fmaxf(la, __shfl_xor(la, 4));
            m = fmaxf(m, __shfl_xor(m, 8));
            float e = __expf(la - m);
            e += __shfl_xor(e, 4);
            e += __shfl_xor(e, 8);
            la -= m + __logf(e);
            m = fmaxf(la, __shfl_xor(la, 1));
            m = fmaxf(m, __shfl_xor(m, 2));
            e = __expf(la - m);
            e += __shfl_xor(e, 1);
            e += __shfl_xor(e, 2);
            la -= m + __logf(e);
        }
        coefS[rr][t * 4 + s] = ap * bt + __expf(la);
    }
    __syncthreads();

    // ---------- P4: mix + store (rolled, packed FMA) ----------
    float cf[16];
#pragma unroll
    for (int i = 0; i < 16; ++i) cf[i] = coefS[r][i];
    float* ob = out + ((size_t)(b * 4) * NN + (n0 + r)) * DD;
#pragma unroll 1
    for (int qq = 0; qq < 4; ++qq) {
        const int dp = (rem + 128 * qq) * 2;    // u32 index within s-plane
        f32x4 dv4[4];
#pragma unroll
        for (int s = 0; s < 4; ++s) {
            u32x2 u = *(const u32x2*)&dTp[r][s * 1024 + dp];
            dv4[s] = (f32x4){blo(u[0]), bhi(u[0]), blo(u[1]), bhi(u[1])};
        }
#pragma unroll
        for (int t = 0; t < 4; ++t) {
            f32x4 o = cf[t * 4 + 0] * dv4[0];
            o += cf[t * 4 + 1] * dv4[1];
            o += cf[t * 4 + 2] * dv4[2];
            o += cf[t * 4 + 3] * dv4[3];
            __builtin_nontemporal_store(o, (f32x4*)(ob + (size_t)t * NN * DD + dp * 2));
        }
    }
}

extern "C" void kernel_launch(void* const* d_in, const int* in_sizes, int n_in,
                              void* d_out, int out_size, void* d_ws, size_t ws_size,
                              hipStream_t stream) {
    const float* residuals = (const float*)d_in[0];
    const float* gamma     = (const float*)d_in[1];
    const float* daf       = (const float*)d_in[2];
    const float* sa        = (const float*)d_in[3];
    const float* pbs       = (const float*)d_in[4];
    const float* rsc       = (const float*)d_in[5];
    const float* dbf       = (const float*)d_in[6];
    const float* sb        = (const float*)d_in[7];
    const float* hps       = (const float*)d_in[8];
    float* out = (float*)d_out;

    unsigned short* Wbf = (unsigned short*)d_ws;    // 32*8192 bf16 = 512 KiB

    k0_prep<<<1024, 256, 0, stream>>>(gamma, daf, dbf, Wbf);
    kf<<<NROWS / 4, 512, 0, stream>>>(residuals, Wbf, sa, sb, pbs, rsc, hps, out);
}

// Round 13
// 204.397 us; speedup vs baseline: 1.0962x; 1.0962x over previous
//
#include <hip/hip_runtime.h>
#include <hip/hip_bf16.h>

typedef float f32x4 __attribute__((ext_vector_type(4)));
typedef float f32x16 __attribute__((ext_vector_type(16)));
typedef unsigned int u32;
typedef u32 u32x2 __attribute__((ext_vector_type(2)));
typedef u32 u32x4 __attribute__((ext_vector_type(4)));
typedef short bf16x8 __attribute__((ext_vector_type(8)));   // 8 bf16 (guide §3 convention)

#define SD 8192      // S*D
#define NROWS 8192   // B*N
#define NN 4096      // N
#define DD 2048      // D
#define DTP 4104     // padded u32 row stride for dT (+8 u32 -> A-frag reads conflict-free)

__device__ __forceinline__ u32 bfr(float f) {   // f32 -> bf16 bits, RNE (K0 only)
    u32 u = __float_as_uint(f);
    return (u + 0x7fffu + ((u >> 16) & 1u)) >> 16;
}
__device__ __forceinline__ float blo(u32 u) { return __uint_as_float(u << 16); }
__device__ __forceinline__ float bhi(u32 u) { return __uint_as_float(u & 0xffff0000u); }

// K0: Wbf[k][j] = bf16( w[j][k] * (gamma[j]+1) ), k 0..31; rows 24..31 zeroed
// (they feed MFMA B-cols 24..31 whose outputs are discarded -- must be finite).
__global__ void k0_prep(const float* __restrict__ gamma,
                        const float* __restrict__ daf,
                        const float* __restrict__ dbf,
                        unsigned short* __restrict__ Wbf) {
    int idx = blockIdx.x * 256 + threadIdx.x;
    if (idx >= 32 * SD) return;
    int k = idx >> 13;
    int j = idx & (SD - 1);
    unsigned short v = 0;
    if (k < 24) {
        float g = gamma[j] + 1.0f;
        float w = (k < 20) ? daf[j * 20 + k] : dbf[j * 4 + (k - 20)];
        v = (unsigned short)bfr(w * g);
    }
    Wbf[(size_t)k * SD + j] = v;
}

// KF: fused, spill-proof, projection on MFMA with GROUP-PREFETCHED B operand.
// Block = 4 rows, 512 threads (8 waves), ~70 KiB LDS -> 2 blocks/CU.
// P1: rows f32->reg (ssq via packed FMA) -> bf16 LDS via v_cvt_pk_bf16_f32.
// P2: projection as MFMA 32x32x16, wave wv owns j-slice 1024 (64 K-steps).
//     R12 lesson: B from global per-step is a serial L2-latency chain (MLP 2).
//     Now: 8 rolled groups x 8 unrolled steps; all 8 independent B loads issue
//     first (MLP 8, compiler emits counted vmcnt), then 8 x (LDS A-read+MFMA).
//     Live ~70 regs (bu 32 + acc 16), no spill. A/B/C layouts R12-verified.
// P3: wave 0: 20-iter sinkhorn + coeff.
// P4: mix from LDS with f32x4 vector FMAs, nt stores.
__global__ __launch_bounds__(512) void kf(const float* __restrict__ res,
                                          const unsigned short* __restrict__ Wbf,
                                          const float* __restrict__ sa,
                                          const float* __restrict__ sb,
                                          const float* __restrict__ pbs,
                                          const float* __restrict__ rsc,
                                          const float* __restrict__ hps,
                                          float* __restrict__ out) {
    __shared__ u32 dTp[4][DTP];        // packed bf16x2; 65.7 KiB
    __shared__ float pc[8][4][32];     // per-wave partial C
    __shared__ float red[4][32];
    __shared__ float ssqw[8];
    __shared__ float coefS[4][16];

    const int tid  = threadIdx.x;
    const int wv   = tid >> 6;
    const int lane = tid & 63;
    const int row0 = blockIdx.x * 4;
    const int b    = row0 >> 12;
    const int n0   = row0 & (NN - 1);
    const int r    = tid >> 7;          // staging/mix row 0..3
    const int rem  = tid & 127;

    // ---------- P1: stage 4 rows, ssq, pack bf16 (cvt_pk) ----------
    const float* rowbase = res + ((size_t)(b * 4) * NN + (n0 + r)) * DD;
    f32x4 ssq4 = {0.f, 0.f, 0.f, 0.f};
#pragma unroll 1
    for (int h = 0; h < 4; ++h) {
        f32x4 v[4];
#pragma unroll
        for (int i = 0; i < 4; ++i) {
            const int q  = h * 4 + i;
            const int j0 = (rem + 128 * q) * 4;
            const int s  = j0 >> 11, d = j0 & 2047;
            v[i] = __builtin_nontemporal_load((const f32x4*)(rowbase + (size_t)s * NN * DD + d));
        }
#pragma unroll
        for (int i = 0; i < 4; ++i) {
            ssq4 += v[i] * v[i];
            u32 lo, hi;
            asm("v_cvt_pk_bf16_f32 %0, %1, %2" : "=v"(lo) : "v"(v[i].x), "v"(v[i].y));
            asm("v_cvt_pk_bf16_f32 %0, %1, %2" : "=v"(hi) : "v"(v[i].z), "v"(v[i].w));
            const int jp = (rem + 128 * (h * 4 + i)) * 2;
            *(u32x2*)&dTp[r][jp] = (u32x2){lo, hi};
        }
    }
    float ssq = ssq4.x + ssq4.y + ssq4.z + ssq4.w;
    ssq += __shfl_xor(ssq, 1);  ssq += __shfl_xor(ssq, 2);
    ssq += __shfl_xor(ssq, 4);  ssq += __shfl_xor(ssq, 8);
    ssq += __shfl_xor(ssq, 16); ssq += __shfl_xor(ssq, 32);
    if (lane == 0) ssqw[wv] = ssq;
    __syncthreads();

    // ---------- P2: projection via MFMA, group-prefetched B ----------
    {
        f32x16 acc;
#pragma unroll
        for (int i = 0; i < 16; ++i) acc[i] = 0.f;
        const u32* abase = &dTp[lane & 3][wv * 512 + (lane >> 5) * 4];
        const unsigned short* wbase = Wbf + (size_t)(lane & 31) * SD + wv * 1024 + (lane >> 5) * 8;
#pragma unroll 1
        for (int g = 0; g < 8; ++g) {
            u32x4 bu[8];
#pragma unroll
            for (int s = 0; s < 8; ++s)
                bu[s] = *(const u32x4*)(wbase + (g * 8 + s) * 16);
#pragma unroll
            for (int s = 0; s < 8; ++s) {
                const u32x4 au = *(const u32x4*)(abase + (g * 8 + s) * 8);
                acc = __builtin_amdgcn_mfma_f32_32x32x16_bf16(
                    __builtin_bit_cast(bf16x8, au), __builtin_bit_cast(bf16x8, bu[s]), acc, 0, 0, 0);
            }
        }
        if (lane < 32) {
#pragma unroll
            for (int gg = 0; gg < 4; ++gg) pc[wv][gg][lane] = acc[gg];
        }
    }
    __syncthreads();
    if (tid < 128) {
        const int rr = tid >> 5, c = tid & 31;
        float s = 0.f;
#pragma unroll
        for (int w = 0; w < 8; ++w) s += pc[w][rr][c];
        red[rr][c] = s;
    }
    __syncthreads();

    // ---------- P3: sinkhorn + coeff (wave 0; 4 rows x 16 lanes) ----------
    if (wv == 0) {
        const int rr = lane >> 4, l = lane & 15, s = l >> 2, t = l & 3;
        const float ssqr  = ssqw[2 * rr] + ssqw[2 * rr + 1];
        const float scale = 90.50966799187809f / fmaxf(sqrtf(ssqr), 1e-12f);
        const float P  = red[rr][s * 5 + t + 1];
        const float P0 = red[rr][s * 5];
        const float Pb = red[rr][20 + t];
        float la = scale * P * rsc[0] + sa[s * 5 + t + 1];
        const float a0 = scale * P0 * pbs[0] + sa[s * 5];
        const float ap = 1.f / (1.f + __expf(-a0));
        const float bt = 2.f / (1.f + __expf(-(scale * Pb * hps[0] + sb[t])));
#pragma unroll
        for (int it = 0; it < 20; ++it) {
            float m = fmaxf(la, __shfl_xor(la, 4));
            m = fmaxf(m, __shfl_xor(m, 8));
            float e = __expf(la - m);
            e += __shfl_xor(e, 4);
            e += __shfl_xor(e, 8);
            la -= m + __logf(e);
            m = fmaxf(la, __shfl_xor(la, 1));
            m = fmaxf(m, __shfl_xor(m, 2));
            e = __expf(la - m);
            e += __shfl_xor(e, 1);
            e += __shfl_xor(e, 2);
            la -= m + __logf(e);
        }
        coefS[rr][t * 4 + s] = ap * bt + __expf(la);
    }
    __syncthreads();

    // ---------- P4: mix + store (rolled, packed FMA) ----------
    float cf[16];
#pragma unroll
    for (int i = 0; i < 16; ++i) cf[i] = coefS[r][i];
    float* ob = out + ((size_t)(b * 4) * NN + (n0 + r)) * DD;
#pragma unroll 1
    for (int qq = 0; qq < 4; ++qq) {
        const int dp = (rem + 128 * qq) * 2;    // u32 index within s-plane
        f32x4 dv4[4];
#pragma unroll
        for (int s = 0; s < 4; ++s) {
            u32x2 u = *(const u32x2*)&dTp[r][s * 1024 + dp];
            dv4[s] = (f32x4){blo(u[0]), bhi(u[0]), blo(u[1]), bhi(u[1])};
        }
#pragma unroll
        for (int t = 0; t < 4; ++t) {
            f32x4 o = cf[t * 4 + 0] * dv4[0];
            o += cf[t * 4 + 1] * dv4[1];
            o += cf[t * 4 + 2] * dv4[2];
            o += cf[t * 4 + 3] * dv4[3];
            __builtin_nontemporal_store(o, (f32x4*)(ob + (size_t)t * NN * DD + dp * 2));
        }
    }
}

extern "C" void kernel_launch(void* const* d_in, const int* in_sizes, int n_in,
                              void* d_out, int out_size, void* d_ws, size_t ws_size,
                              hipStream_t stream) {
    const float* residuals = (const float*)d_in[0];
    const float* gamma     = (const float*)d_in[1];
    const float* daf       = (const float*)d_in[2];
    const float* sa        = (const float*)d_in[3];
    const float* pbs       = (const float*)d_in[4];
    const float* rsc       = (const float*)d_in[5];
    const float* dbf       = (const float*)d_in[6];
    const float* sb        = (const float*)d_in[7];
    const float* hps       = (const float*)d_in[8];
    float* out = (float*)d_out;

    unsigned short* Wbf = (unsigned short*)d_ws;    // 32*8192 bf16 = 512 KiB

    k0_prep<<<1024, 256, 0, stream>>>(gamma, daf, dbf, Wbf);
    kf<<<NROWS / 4, 512, 0, stream>>>(residuals, Wbf, sa, sb, pbs, rsc, hps, out);
}

// Round 14
// 152.161 us; speedup vs baseline: 1.4725x; 1.3433x over previous
//
#include <hip/hip_runtime.h>
#include <hip/hip_bf16.h>

typedef float f32x4 __attribute__((ext_vector_type(4)));
typedef float f32x16 __attribute__((ext_vector_type(16)));
typedef unsigned int u32;
typedef u32 u32x2 __attribute__((ext_vector_type(2)));
typedef u32 u32x4 __attribute__((ext_vector_type(4)));
typedef short bf16x8 __attribute__((ext_vector_type(8)));   // 8 bf16 (guide §3 convention)

#define SD 8192      // S*D
#define NROWS 8192   // B*N
#define NN 4096      // N
#define DD 2048      // D
#define DTP 4104     // padded u32 row stride for dT (+8 u32 -> A-frag reads conflict-free)

__device__ __forceinline__ u32 bfr(float f) {   // f32 -> bf16 bits, RNE (K0 only)
    u32 u = __float_as_uint(f);
    return (u + 0x7fffu + ((u >> 16) & 1u)) >> 16;
}
__device__ __forceinline__ float blo(u32 u) { return __uint_as_float(u << 16); }
__device__ __forceinline__ float bhi(u32 u) { return __uint_as_float(u & 0xffff0000u); }

// K0: build weights directly in MFMA B-FRAGMENT order (R13 lesson: the natural
// k-major layout makes every P2 B-load a 64-way 16KB-stride scatter -> 67M L2
// requests chip-wide = the 220us wall. The B matrix is identical for every
// block, so gather ONCE here into per-lane order):
//   Wfrag[((wv*64+st)*64+lane)*8+e] = W[k=lane&31][j=wv*1024+st*16+((lane>>5)&1)*8+e]
// where W[k][j] = (k<20 ? daf[j*20+k] : k<24 ? dbf[j*4+k-20] : 0) * (gamma[j]+1).
__global__ void k0_prep(const float* __restrict__ gamma,
                        const float* __restrict__ daf,
                        const float* __restrict__ dbf,
                        unsigned short* __restrict__ Wfrag) {
    int idx = blockIdx.x * 256 + threadIdx.x;
    if (idx >= 32 * SD) return;
    const int e    = idx & 7;
    const int lane = (idx >> 3) & 63;
    const int st   = (idx >> 9) & 63;
    const int wv   = idx >> 15;
    const int outk = lane & 31;
    const int j    = wv * 1024 + st * 16 + ((lane >> 5) & 1) * 8 + e;
    unsigned short v = 0;
    if (outk < 24) {
        float g = gamma[j] + 1.0f;
        float w = (outk < 20) ? daf[j * 20 + outk] : dbf[j * 4 + (outk - 20)];
        v = (unsigned short)bfr(w * g);
    }
    Wfrag[idx] = v;
}

// KF: fused, spill-proof, projection on MFMA with FRAGMENT-ORDER B loads
// (coalesced 16B/lane). Block = 4 rows, 512 threads (8 waves), 2 blocks/CU.
// P1: rows f32->reg (ssq packed) -> bf16 LDS via v_cvt_pk_bf16_f32.
// P2: MFMA 32x32x16; wave wv owns j-slice 1024 (64 K-steps, 8 groups x 8).
//     A from padded LDS (broadcast, conflict-free); B from Wfrag (coalesced,
//     L2-resident). C layout (m74/m101): valid rows 0..3 = lanes 0..31 regs 0..3.
// P3: wave 0: 20-iter sinkhorn + coeff.  P4: mix from LDS, f32x4 FMAs, nt stores.
__global__ __launch_bounds__(512) void kf(const float* __restrict__ res,
                                          const unsigned short* __restrict__ Wfrag,
                                          const float* __restrict__ sa,
                                          const float* __restrict__ sb,
                                          const float* __restrict__ pbs,
                                          const float* __restrict__ rsc,
                                          const float* __restrict__ hps,
                                          float* __restrict__ out) {
    __shared__ u32 dTp[4][DTP];        // packed bf16x2; 65.7 KiB
    __shared__ float pc[8][4][32];     // per-wave partial C
    __shared__ float red[4][32];
    __shared__ float ssqw[8];
    __shared__ float coefS[4][16];

    const int tid  = threadIdx.x;
    const int wv   = tid >> 6;
    const int lane = tid & 63;
    const int row0 = blockIdx.x * 4;
    const int b    = row0 >> 12;
    const int n0   = row0 & (NN - 1);
    const int r    = tid >> 7;          // staging/mix row 0..3
    const int rem  = tid & 127;

    // ---------- P1: stage 4 rows, ssq, pack bf16 (cvt_pk) ----------
    const float* rowbase = res + ((size_t)(b * 4) * NN + (n0 + r)) * DD;
    f32x4 ssq4 = {0.f, 0.f, 0.f, 0.f};
#pragma unroll 1
    for (int h = 0; h < 4; ++h) {
        f32x4 v[4];
#pragma unroll
        for (int i = 0; i < 4; ++i) {
            const int q  = h * 4 + i;
            const int j0 = (rem + 128 * q) * 4;
            const int s  = j0 >> 11, d = j0 & 2047;
            v[i] = __builtin_nontemporal_load((const f32x4*)(rowbase + (size_t)s * NN * DD + d));
        }
#pragma unroll
        for (int i = 0; i < 4; ++i) {
            ssq4 += v[i] * v[i];
            u32 lo, hi;
            asm("v_cvt_pk_bf16_f32 %0, %1, %2" : "=v"(lo) : "v"(v[i].x), "v"(v[i].y));
            asm("v_cvt_pk_bf16_f32 %0, %1, %2" : "=v"(hi) : "v"(v[i].z), "v"(v[i].w));
            const int jp = (rem + 128 * (h * 4 + i)) * 2;
            *(u32x2*)&dTp[r][jp] = (u32x2){lo, hi};
        }
    }
    float ssq = ssq4.x + ssq4.y + ssq4.z + ssq4.w;
    ssq += __shfl_xor(ssq, 1);  ssq += __shfl_xor(ssq, 2);
    ssq += __shfl_xor(ssq, 4);  ssq += __shfl_xor(ssq, 8);
    ssq += __shfl_xor(ssq, 16); ssq += __shfl_xor(ssq, 32);
    if (lane == 0) ssqw[wv] = ssq;
    __syncthreads();

    // ---------- P2: projection via MFMA, coalesced fragment B ----------
    {
        f32x16 acc;
#pragma unroll
        for (int i = 0; i < 16; ++i) acc[i] = 0.f;
        const u32* abase = &dTp[lane & 3][wv * 512 + (lane >> 5) * 4];
        const unsigned short* wbase = Wfrag + ((size_t)wv * 64 * 64 + lane) * 8;
#pragma unroll 1
        for (int g = 0; g < 8; ++g) {
            u32x4 bu[8];
#pragma unroll
            for (int s = 0; s < 8; ++s)
                bu[s] = *(const u32x4*)(wbase + (size_t)(g * 8 + s) * 64 * 8);
#pragma unroll
            for (int s = 0; s < 8; ++s) {
                const u32x4 au = *(const u32x4*)(abase + (g * 8 + s) * 8);
                acc = __builtin_amdgcn_mfma_f32_32x32x16_bf16(
                    __builtin_bit_cast(bf16x8, au), __builtin_bit_cast(bf16x8, bu[s]), acc, 0, 0, 0);
            }
        }
        if (lane < 32) {
#pragma unroll
            for (int gg = 0; gg < 4; ++gg) pc[wv][gg][lane] = acc[gg];
        }
    }
    __syncthreads();
    if (tid < 128) {
        const int rr = tid >> 5, c = tid & 31;
        float s = 0.f;
#pragma unroll
        for (int w = 0; w < 8; ++w) s += pc[w][rr][c];
        red[rr][c] = s;
    }
    __syncthreads();

    // ---------- P3: sinkhorn + coeff (wave 0; 4 rows x 16 lanes) ----------
    if (wv == 0) {
        const int rr = lane >> 4, l = lane & 15, s = l >> 2, t = l & 3;
        const float ssqr  = ssqw[2 * rr] + ssqw[2 * rr + 1];
        const float scale = 90.50966799187809f / fmaxf(sqrtf(ssqr), 1e-12f);
        const float P  = red[rr][s * 5 + t + 1];
        const float P0 = red[rr][s * 5];
        const float Pb = red[rr][20 + t];
        float la = scale * P * rsc[0] + sa[s * 5 + t + 1];
        const float a0 = scale * P0 * pbs[0] + sa[s * 5];
        const float ap = 1.f / (1.f + __expf(-a0));
        const float bt = 2.f / (1.f + __expf(-(scale * Pb * hps[0] + sb[t])));
#pragma unroll
        for (int it = 0; it < 20; ++it) {
            float m = fmaxf(la, __shfl_xor(la, 4));
            m = fmaxf(m, __shfl_xor(m, 8));
            float e = __expf(la - m);
            e += __shfl_xor(e, 4);
            e += __shfl_xor(e, 8);
            la -= m + __logf(e);
            m = fmaxf(la, __shfl_xor(la, 1));
            m = fmaxf(m, __shfl_xor(m, 2));
            e = __expf(la - m);
            e += __shfl_xor(e, 1);
            e += __shfl_xor(e, 2);
            la -= m + __logf(e);
        }
        coefS[rr][t * 4 + s] = ap * bt + __expf(la);
    }
    __syncthreads();

    // ---------- P4: mix + store (rolled, packed FMA) ----------
    float cf[16];
#pragma unroll
    for (int i = 0; i < 16; ++i) cf[i] = coefS[r][i];
    float* ob = out + ((size_t)(b * 4) * NN + (n0 + r)) * DD;
#pragma unroll 1
    for (int qq = 0; qq < 4; ++qq) {
        const int dp = (rem + 128 * qq) * 2;    // u32 index within s-plane
        f32x4 dv4[4];
#pragma unroll
        for (int s = 0; s < 4; ++s) {
            u32x2 u = *(const u32x2*)&dTp[r][s * 1024 + dp];
            dv4[s] = (f32x4){blo(u[0]), bhi(u[0]), blo(u[1]), bhi(u[1])};
        }
#pragma unroll
        for (int t = 0; t < 4; ++t) {
            f32x4 o = cf[t * 4 + 0] * dv4[0];
            o += cf[t * 4 + 1] * dv4[1];
            o += cf[t * 4 + 2] * dv4[2];
            o += cf[t * 4 + 3] * dv4[3];
            __builtin_nontemporal_store(o, (f32x4*)(ob + (size_t)t * NN * DD + dp * 2));
        }
    }
}

extern "C" void kernel_launch(void* const* d_in, const int* in_sizes, int n_in,
                              void* d_out, int out_size, void* d_ws, size_t ws_size,
                              hipStream_t stream) {
    const float* residuals = (const float*)d_in[0];
    const float* gamma     = (const float*)d_in[1];
    const float* daf       = (const float*)d_in[2];
    const float* sa        = (const float*)d_in[3];
    const float* pbs       = (const float*)d_in[4];
    const float* rsc       = (const float*)d_in[5];
    const float* dbf       = (const float*)d_in[6];
    const float* sb        = (const float*)d_in[7];
    const float* hps       = (const float*)d_in[8];
    float* out = (float*)d_out;

    unsigned short* Wfrag = (unsigned short*)d_ws;  // 32*8192 bf16 = 512 KiB, fragment order

    k0_prep<<<1024, 256, 0, stream>>>(gamma, daf, dbf, Wfrag);
    kf<<<NROWS / 4, 512, 0, stream>>>(residuals, Wfrag, sa, sb, pbs, rsc, hps, out);
}